// Round 20
// baseline (157.368 us; speedup 1.0000x reference)
//
#include <hip/hip_runtime.h>
#include <hip/hip_bf16.h>
#include <cstddef>
#include <cstdint>

#define NN 4096
#define BB 128

using short8 = __attribute__((ext_vector_type(8))) short;
using f32x4  = __attribute__((ext_vector_type(4))) float;

__device__ __forceinline__ void klims(int r, int& S, int& E) {
    if (r == 0) { S = 0; E = 1; return; }
    int j = (31 - __clz(r)) >> 1;
    int g = r >> (2 * j);
    S = g << (2 * j);
    E = (g + 1) << (2 * j);
}

__device__ __forceinline__ int perm_site(int n) {
    if (n == 0) return 0;
    int j = (31 - __clz(n)) >> 1;
    int g = n >> (2 * j);
    int o = n - (g << (2 * j));
    int side = 1 << j;
    int rr = o >> j, cc = o & (side - 1);
    int i = 5 - j;
    int s = 1 << i, p = 1 << (i + 1);
    int r, c;
    if (g == 1)      { r = s + rr * p; c = s + cc * p; }
    else if (g == 2) { r = s + rr * p; c = cc * p;     }
    else             { r = rr * p;     c = s + cc * p; }
    return r * 64 + c;
}

__device__ __forceinline__ int inv_site(int s) {
    if (s == 0) return 0;
    int r = s >> 6, c = s & 63;
    int ir = r ? __builtin_ctz(r) : 6;
    int ic = c ? __builtin_ctz(c) : 6;
    int i = ir < ic ? ir : ic;
    int j = 5 - i;
    int rb = (r >> i) & 1, cb = (c >> i) & 1;
    int g = rb ? (cb ? 1 : 2) : 3;
    return (g << (2 * j)) + ((r >> (i + 1)) << j) + (c >> (i + 1));
}

__device__ __forceinline__ size_t fidx(int k, int b) {
    return (size_t)(((k >> 5) * 8 + (b >> 4)) * 512 + ((k >> 2) & 3) * 128 +
                    (b & 15) * 8 + ((k >> 4) & 1) * 4 + (k & 3));
}

__device__ __forceinline__ unsigned short f2bf(float f) {
    __hip_bfloat16 h = __float2bfloat16(f);
    return __builtin_bit_cast(unsigned short, h);
}

__device__ __forceinline__ float bf2f(unsigned short u) {
    unsigned v = (unsigned)u << 16;
    return __builtin_bit_cast(float, v);
}

__device__ __forceinline__ void gload_lds16(const void* g, void* l) {
    __builtin_amdgcn_global_load_lds(
        (const __attribute__((address_space(1))) unsigned int*)g,
        (__attribute__((address_space(3))) unsigned int*)l, 16, 0, 0);
}

__device__ __forceinline__ int tile_nt(int M, int tile, int nseg, int excl) {
    int r_top = (M - 1 - tile * 128) & (NN - 1);
    int S, E;
    klims(r_top, S, E);
    int kmax = excl ? S : E;
    return nseg * ((kmax + 63) >> 6);
}

// fold: xf_frag[n][b] = x[b][site(n)] as bf16, coalesced reads over x
__global__ void fold_k(const float* __restrict__ x, unsigned short* __restrict__ xf) {
    int gid = blockIdx.x * 256 + threadIdx.x;  // b*4096 + s
    int b = gid >> 12, s = gid & 4095;
    float v = x[gid];
    int n = inv_site(s);
    xf[fidx(n, b)] = f2bf(v);
}

// Masked GEMM (champion body) + W BURST-2: W held in two PAIR buffers
// (2 k-steps each); each pair's 8 dwordx4 issued back-to-back so every
// W row is read in 512B sequential bursts (halves DRAM row-activations).
template <bool EXCL>
__global__ __launch_bounds__(512, 2) void made_gemm20(
        const unsigned short* __restrict__ A, const float* __restrict__ W,
        unsigned short* __restrict__ partial, int M, int Ktot, int nseg, int CH) {
    __shared__ __align__(16) char lds[32768];   // 2 x 16KB A k-step buffers

    int b = (int)blockIdx.x, tile = 0, base = 0, nt = 0;
    for (;;) {
        nt = tile_nt(M, tile, nseg, EXCL ? 1 : 0);
        int cnt = (nt + CH - 1) / CH;
        if (b < base + cnt) break;
        base += cnt;
        ++tile;
    }
    const int nkt = nt / nseg;
    const int t0 = (b - base) * CH;
    const int t1 = (t0 + CH < nt) ? t0 + CH : nt;

    const int tid  = threadIdx.x;
    const int wid  = tid >> 6;
    const int lane = tid & 63;
    const int r0   = M - 128 - tile * 128;
    const int rw0  = r0 + wid * 16;
    const int rch  = rw0 & (NN - 1);
    const int row  = lane & 15;
    const int kq   = lane >> 4;

    int S, E;
    klims(rch + row, S, E);
    const int kl = EXCL ? S : E;
    klims(rch, S, E);
    const int wkmin = EXCL ? S : E;

    f32x4 acc[8] = {};
    const float* wrow = W + (size_t)(rw0 + row) * Ktot + kq * 4;
    const char* Ab = (const char*)A;

    float4 wA[8], wB[8];   // two PAIR buffers: [0..3]=first k-step, [4..7]=second

// burst: issue W(T) and W(T+1) back-to-back (T+1 clamped inside [t0,t1))
#define ISSUE_W2(T, WB)                                                       \
    {                                                                         \
        int Ta_ = (T);                                                        \
        int Tb_ = (Ta_ + 1 < t1) ? Ta_ + 1 : Ta_;                             \
        int sga_ = (nseg == 2 && Ta_ >= nkt) ? 1 : 0;                         \
        const float* wpa_ = wrow + sga_ * NN + ((Ta_ - sga_ * nkt) << 6);     \
        int sgb_ = (nseg == 2 && Tb_ >= nkt) ? 1 : 0;                         \
        const float* wpb_ = wrow + sgb_ * NN + ((Tb_ - sgb_ * nkt) << 6);     \
        WB[0] = *(const float4*)(wpa_);                                       \
        WB[1] = *(const float4*)(wpa_ + 16);                                  \
        WB[2] = *(const float4*)(wpa_ + 32);                                  \
        WB[3] = *(const float4*)(wpa_ + 48);                                  \
        WB[4] = *(const float4*)(wpb_);                                       \
        WB[5] = *(const float4*)(wpb_ + 16);                                  \
        WB[6] = *(const float4*)(wpb_ + 32);                                  \
        WB[7] = *(const float4*)(wpb_ + 48);                                  \
    }

#define STAGE_A(T, BUF)                                                       \
    {                                                                         \
        int sg_ = (nseg == 2 && (T) >= nkt) ? 1 : 0;                          \
        int kb_ = ((T) - sg_ * nkt) << 6;                                     \
        const char* src_ = Ab + (size_t)(sg_ * NN + kb_) * 256 +              \
                           wid * 2048 + lane * 16;                            \
        char* dst_ = lds + (BUF) * 16384 + wid * 2048;                        \
        gload_lds16(src_, dst_);                                              \
        gload_lds16(src_ + 1024, dst_ + 1024);                                \
    }

#define COMPUTE_L(T, BUF, WARR, HO)                                           \
    {                                                                         \
        int kb_ = (((T) >= nkt && nseg == 2) ? (T) - nkt : (T)) << 6;         \
        float wv_[16];                                                        \
        _Pragma("unroll")                                                     \
        for (int i_ = 0; i_ < 4; ++i_) {                                      \
            wv_[4 * i_ + 0] = WARR[(HO) + i_].x;                              \
            wv_[4 * i_ + 1] = WARR[(HO) + i_].y;                              \
            wv_[4 * i_ + 2] = WARR[(HO) + i_].z;                              \
            wv_[4 * i_ + 3] = WARR[(HO) + i_].w;                              \
        }                                                                     \
        if (kb_ + 64 > wkmin) {                                               \
            int k0_ = kb_ + kq * 4;                                           \
            _Pragma("unroll")                                                 \
            for (int i_ = 0; i_ < 4; ++i_) {                                  \
                _Pragma("unroll")                                             \
                for (int j_ = 0; j_ < 4; ++j_)                                \
                    if (k0_ + i_ * 16 + j_ >= kl) wv_[4 * i_ + j_] = 0.0f;    \
            }                                                                 \
        }                                                                     \
        short8 wf0_, wf1_;                                                    \
        _Pragma("unroll")                                                     \
        for (int e_ = 0; e_ < 8; ++e_) {                                      \
            wf0_[e_] = (short)f2bf(wv_[e_]);                                  \
            wf1_[e_] = (short)f2bf(wv_[8 + e_]);                              \
        }                                                                     \
        const char* ab_ = lds + (BUF) * 16384 + lane * 16;                    \
        _Pragma("unroll")                                                     \
        for (int q_ = 0; q_ < 8; ++q_) {                                      \
            short8 a0_ = *(const short8*)(ab_ + q_ * 1024);                   \
            short8 a1_ = *(const short8*)(ab_ + 8192 + q_ * 1024);            \
            acc[q_] = __builtin_amdgcn_mfma_f32_16x16x32_bf16(                \
                wf0_, a0_, acc[q_], 0, 0, 0);                                 \
            acc[q_] = __builtin_amdgcn_mfma_f32_16x16x32_bf16(                \
                wf1_, a1_, acc[q_], 0, 0, 0);                                 \
        }                                                                     \
    }

    {
        int t = t0, buf = 0;
        STAGE_A(t, 0);
        ISSUE_W2(t, wA);
        while (true) {
            // pair 0 on wA, first half
            __syncthreads();
            bool pre = (t + 1 < t1);
            if (pre) STAGE_A(t + 1, buf ^ 1);
            if (t + 2 < t1) ISSUE_W2(t + 2, wB);
            COMPUTE_L(t, buf, wA, 0);
            if (!pre) break;
            ++t; buf ^= 1;
            // pair 0 on wA, second half
            __syncthreads();
            pre = (t + 1 < t1);
            if (pre) STAGE_A(t + 1, buf ^ 1);
            COMPUTE_L(t, buf, wA, 4);
            if (!pre) break;
            ++t; buf ^= 1;
            // pair 1 on wB, first half
            __syncthreads();
            pre = (t + 1 < t1);
            if (pre) STAGE_A(t + 1, buf ^ 1);
            if (t + 2 < t1) ISSUE_W2(t + 2, wA);
            COMPUTE_L(t, buf, wB, 0);
            if (!pre) break;
            ++t; buf ^= 1;
            // pair 1 on wB, second half
            __syncthreads();
            pre = (t + 1 < t1);
            if (pre) STAGE_A(t + 1, buf ^ 1);
            COMPUTE_L(t, buf, wB, 4);
            if (!pre) break;
            ++t; buf ^= 1;
        }
    }
#undef ISSUE_W2
#undef STAGE_A
#undef COMPUTE_L

    // bf16 partial tile [128 rows][128 b] at this block's 32KB slot
    unsigned short* pc = partial + (size_t)blockIdx.x * 16384 +
                         (wid * 16 + kq * 4) * 128 + row;
#pragma unroll
    for (int q = 0; q < 8; ++q)
#pragma unroll
        for (int i = 0; i < 4; ++i)
            pc[(size_t)i * 128 + q * 16] = f2bf(acc[q][i]);
}

// reduce bf16 partial slots + bias + prelu -> bf16 fragment-order activations
__global__ void reduce01_k(const unsigned short* __restrict__ p,
                           const float* __restrict__ bias,
                           const float* __restrict__ alpha, unsigned short* __restrict__ h,
                           int M, int nseg, int excl, int CH) {
    int gid = blockIdx.x * 256 + threadIdx.x;   // (M/4)*128 threads
    int m0 = (gid >> 7) << 2;
    int b  = gid & 127;
    int tile_m = (M - 128 - (m0 & ~127)) >> 7;
    int basep = 0, cntm = 0;
    for (int tt = 0; tt <= tile_m; ++tt) {
        int nt = tile_nt(M, tt, nseg, excl);
        int cnt = (nt + CH - 1) / CH;
        if (tt == tile_m) cntm = cnt;
        else basep += cnt;
    }
    const unsigned short* ps = p + (size_t)basep * 16384 + (m0 & 127) * 128 + b;
    f32x4 v = {};
    for (int s = 0; s < cntm; ++s) {
        v[0] += bf2f(ps[0]);
        v[1] += bf2f(ps[128]);
        v[2] += bf2f(ps[256]);
        v[3] += bf2f(ps[384]);
        ps += 16384;
    }
    ushort4 st;
    float t;
    t = v[0] + bias[m0 + 0]; t = fmaxf(t, 0.f) + alpha[m0 + 0] * fminf(t, 0.f); st.x = f2bf(t);
    t = v[1] + bias[m0 + 1]; t = fmaxf(t, 0.f) + alpha[m0 + 1] * fminf(t, 0.f); st.y = f2bf(t);
    t = v[2] + bias[m0 + 2]; t = fmaxf(t, 0.f) + alpha[m0 + 2] * fminf(t, 0.f); st.z = f2bf(t);
    t = v[3] + bias[m0 + 3]; t = fmaxf(t, 0.f) + alpha[m0 + 3] * fminf(t, 0.f); st.w = f2bf(t);
    *(ushort4*)&h[fidx(m0, b)] = st;
}

// reduce bf16 partial slots + bias + sigmoid + unfold scatter -> out[b][site]
__global__ void reduce2_k(const unsigned short* __restrict__ p,
                          const float* __restrict__ b2,
                          float* __restrict__ out, int CH) {
    int gid = blockIdx.x * 256 + threadIdx.x;   // NN*BB threads, n-major
    int n = gid >> 7;
    int b = gid & 127;
    int tile_m = (NN - 128 - (n & ~127)) >> 7;
    int basep = 0, cntm = 0;
    for (int tt = 0; tt <= tile_m; ++tt) {
        int nt = tile_nt(NN, tt, 2, 0);
        int cnt = (nt + CH - 1) / CH;
        if (tt == tile_m) cntm = cnt;
        else basep += cnt;
    }
    const unsigned short* ps = p + (size_t)basep * 16384 + (n & 127) * 128 + b;
    float v = 0.0f;
    for (int s = 0; s < cntm; ++s) { v += bf2f(*ps); ps += 16384; }
    v += b2[n];
    float sg = 1.0f / (1.0f + __expf(-v));
    if (n == 0) sg = 0.5f;
    out[(size_t)b * NN + perm_site(n)] = sg;
}

// ---------------- host ----------------
static inline void h_klims(int r, int& S, int& E) {
    if (r == 0) { S = 0; E = 1; return; }
    int j = (31 - __builtin_clz((unsigned)r)) >> 1;
    int g = r >> (2 * j);
    S = g << (2 * j);
    E = (g + 1) << (2 * j);
}

static inline int grid_for(int M, int nseg, int excl, int CH) {
    int nb = 0;
    for (int tile = 0; tile < M / 128; ++tile) {
        int r_top = (M - 1 - tile * 128) & (NN - 1);
        int S, E;
        h_klims(r_top, S, E);
        int kmax = excl ? S : E;
        int nt = nseg * ((kmax + 63) >> 6);
        nb += (nt + CH - 1) / CH;
    }
    return nb;
}

// smallest CH with grid <= cap AND partial buffer fits -> largest grid <= cap
static inline int pick_ch(int M, int nseg, int excl, int cap, size_t ws_avail,
                          int* g_out) {
    for (int ch = 2; ch <= 4096; ++ch) {
        int g = grid_for(M, nseg, excl, ch);
        if (g <= cap && (size_t)g * 32768 <= ws_avail) {
            *g_out = g;
            return ch;
        }
    }
    *g_out = grid_for(M, nseg, excl, 4096);
    return 4096;
}

extern "C" void kernel_launch(void* const* d_in, const int* in_sizes, int n_in,
                              void* d_out, int out_size, void* d_ws, size_t ws_size,
                              hipStream_t stream) {
    const float* x  = (const float*)d_in[0];
    const float* W0 = (const float*)d_in[1];
    const float* b0 = (const float*)d_in[2];
    const float* a1 = (const float*)d_in[3];
    const float* W1 = (const float*)d_in[4];
    const float* b1 = (const float*)d_in[5];
    const float* a2 = (const float*)d_in[6];
    const float* W2 = (const float*)d_in[7];
    const float* b2 = (const float*)d_in[8];

    char* ws = (char*)d_ws;
    unsigned short* xf = (unsigned short*)ws;                 // 1 MB
    unsigned short* h0 = (unsigned short*)(ws + (1 << 20));   // 2 MB
    unsigned short* h1 = (unsigned short*)(ws + (3 << 20));   // 2 MB
    unsigned short* pp = (unsigned short*)(ws + (5 << 20));   // bf16 partials (32KB/slot)

    size_t avail = ws_size > (5u << 20) ? ws_size - (5u << 20) : 0;
    int g0, g1, g2;
    int CH0 = pick_ch(2 * NN, 1, 1, 512, avail, &g0);
    int CH1 = pick_ch(2 * NN, 2, 0, 512, avail, &g1);
    int CH2 = pick_ch(NN, 2, 0, 512, avail, &g2);

    fold_k<<<2048, 256, 0, stream>>>(x, xf);

    made_gemm20<true><<<g0, 512, 0, stream>>>(xf, W0, pp, 2 * NN, NN, 1, CH0);
    reduce01_k<<<1024, 256, 0, stream>>>(pp, b0, a1, h0, 2 * NN, 1, 1, CH0);

    made_gemm20<false><<<g1, 512, 0, stream>>>(h0, W1, pp, 2 * NN, 2 * NN, 2, CH1);
    reduce01_k<<<1024, 256, 0, stream>>>(pp, b1, a2, h1, 2 * NN, 2, 0, CH1);

    made_gemm20<false><<<g2, 512, 0, stream>>>(h1, W2, pp, NN, 2 * NN, 2, CH2);
    reduce2_k<<<2048, 256, 0, stream>>>(pp, b2, (float*)d_out, CH2);
}

// Round 21
// 153.753 us; speedup vs baseline: 1.0235x; 1.0235x over previous
//
#include <hip/hip_runtime.h>
#include <hip/hip_bf16.h>
#include <cstddef>
#include <cstdint>

#define NN 4096
#define BB 128

using short8 = __attribute__((ext_vector_type(8))) short;
using f32x4  = __attribute__((ext_vector_type(4))) float;

__device__ __forceinline__ void klims(int r, int& S, int& E) {
    if (r == 0) { S = 0; E = 1; return; }
    int j = (31 - __clz(r)) >> 1;
    int g = r >> (2 * j);
    S = g << (2 * j);
    E = (g + 1) << (2 * j);
}

__device__ __forceinline__ int perm_site(int n) {
    if (n == 0) return 0;
    int j = (31 - __clz(n)) >> 1;
    int g = n >> (2 * j);
    int o = n - (g << (2 * j));
    int side = 1 << j;
    int rr = o >> j, cc = o & (side - 1);
    int i = 5 - j;
    int s = 1 << i, p = 1 << (i + 1);
    int r, c;
    if (g == 1)      { r = s + rr * p; c = s + cc * p; }
    else if (g == 2) { r = s + rr * p; c = cc * p;     }
    else             { r = rr * p;     c = s + cc * p; }
    return r * 64 + c;
}

__device__ __forceinline__ int inv_site(int s) {
    if (s == 0) return 0;
    int r = s >> 6, c = s & 63;
    int ir = r ? __builtin_ctz(r) : 6;
    int ic = c ? __builtin_ctz(c) : 6;
    int i = ir < ic ? ir : ic;
    int j = 5 - i;
    int rb = (r >> i) & 1, cb = (c >> i) & 1;
    int g = rb ? (cb ? 1 : 2) : 3;
    return (g << (2 * j)) + ((r >> (i + 1)) << j) + (c >> (i + 1));
}

__device__ __forceinline__ size_t fidx(int k, int b) {
    return (size_t)(((k >> 5) * 8 + (b >> 4)) * 512 + ((k >> 2) & 3) * 128 +
                    (b & 15) * 8 + ((k >> 4) & 1) * 4 + (k & 3));
}

__device__ __forceinline__ unsigned short f2bf(float f) {
    __hip_bfloat16 h = __float2bfloat16(f);
    return __builtin_bit_cast(unsigned short, h);
}

__device__ __forceinline__ float bf2f(unsigned short u) {
    unsigned v = (unsigned)u << 16;
    return __builtin_bit_cast(float, v);
}

// nt load for stream-once W (native ext-vector type; HIP float4 rejected)
__device__ __forceinline__ f32x4 nt_load4(const float* p) {
    return __builtin_nontemporal_load((const f32x4*)p);
}

__device__ __forceinline__ void gload_lds16(const void* g, void* l) {
    __builtin_amdgcn_global_load_lds(
        (const __attribute__((address_space(1))) unsigned int*)g,
        (__attribute__((address_space(3))) unsigned int*)l, 16, 0, 0);
}

__device__ __forceinline__ int tile_nt(int M, int tile, int nseg, int excl) {
    int r_top = (M - 1 - tile * 128) & (NN - 1);
    int S, E;
    klims(r_top, S, E);
    int kmax = excl ? S : E;
    return nseg * ((kmax + 63) >> 6);
}

// fold: xf_frag[n][b] = x[b][site(n)] as bf16, coalesced reads over x
__global__ void fold_k(const float* __restrict__ x, unsigned short* __restrict__ xf) {
    int gid = blockIdx.x * 256 + threadIdx.x;  // b*4096 + s
    int b = gid >> 12, s = gid & 4095;
    float v = x[gid];
    int n = inv_site(s);
    xf[fidx(n, b)] = f2bf(v);
}

// Masked GEMM (R19 champion body, W loads NON-TEMPORAL only):
// flattened queue, A LDS-staged dbuf, W 2-deep reg prefetch, bf16 partials,
// CH tuned so grid <= 512 (one dispatch round).
template <bool EXCL>
__global__ __launch_bounds__(512, 2) void made_gemm21(
        const unsigned short* __restrict__ A, const float* __restrict__ W,
        unsigned short* __restrict__ partial, int M, int Ktot, int nseg, int CH) {
    __shared__ __align__(16) char lds[32768];   // 2 x 16KB A k-step buffers

    int b = (int)blockIdx.x, tile = 0, base = 0, nt = 0;
    for (;;) {
        nt = tile_nt(M, tile, nseg, EXCL ? 1 : 0);
        int cnt = (nt + CH - 1) / CH;
        if (b < base + cnt) break;
        base += cnt;
        ++tile;
    }
    const int nkt = nt / nseg;
    const int t0 = (b - base) * CH;
    const int t1 = (t0 + CH < nt) ? t0 + CH : nt;

    const int tid  = threadIdx.x;
    const int wid  = tid >> 6;
    const int lane = tid & 63;
    const int r0   = M - 128 - tile * 128;
    const int rw0  = r0 + wid * 16;
    const int rch  = rw0 & (NN - 1);
    const int row  = lane & 15;
    const int kq   = lane >> 4;

    int S, E;
    klims(rch + row, S, E);
    const int kl = EXCL ? S : E;
    klims(rch, S, E);
    const int wkmin = EXCL ? S : E;

    f32x4 acc[8] = {};
    const float* wrow = W + (size_t)(rw0 + row) * Ktot + kq * 4;
    const char* Ab = (const char*)A;

    f32x4 wbA[4], wbB[4];

#define ISSUE_W(T, WB)                                                        \
    {                                                                         \
        int sg_ = (nseg == 2 && (T) >= nkt) ? 1 : 0;                          \
        const float* wp_ = wrow + sg_ * NN + (((T) - sg_ * nkt) << 6);        \
        WB[0] = nt_load4(wp_);                                                \
        WB[1] = nt_load4(wp_ + 16);                                           \
        WB[2] = nt_load4(wp_ + 32);                                           \
        WB[3] = nt_load4(wp_ + 48);                                           \
    }

#define STAGE_A(T, BUF)                                                       \
    {                                                                         \
        int sg_ = (nseg == 2 && (T) >= nkt) ? 1 : 0;                          \
        int kb_ = ((T) - sg_ * nkt) << 6;                                     \
        const char* src_ = Ab + (size_t)(sg_ * NN + kb_) * 256 +              \
                           wid * 2048 + lane * 16;                            \
        char* dst_ = lds + (BUF) * 16384 + wid * 2048;                        \
        gload_lds16(src_, dst_);                                              \
        gload_lds16(src_ + 1024, dst_ + 1024);                                \
    }

#define COMPUTE_L(T, BUF, WB)                                                 \
    {                                                                         \
        int kb_ = (((T) >= nkt && nseg == 2) ? (T) - nkt : (T)) << 6;         \
        float wv_[16];                                                        \
        _Pragma("unroll")                                                     \
        for (int i_ = 0; i_ < 4; ++i_) {                                      \
            wv_[4 * i_ + 0] = WB[i_][0];                                      \
            wv_[4 * i_ + 1] = WB[i_][1];                                      \
            wv_[4 * i_ + 2] = WB[i_][2];                                      \
            wv_[4 * i_ + 3] = WB[i_][3];                                      \
        }                                                                     \
        if (kb_ + 64 > wkmin) {                                               \
            int k0_ = kb_ + kq * 4;                                           \
            _Pragma("unroll")                                                 \
            for (int i_ = 0; i_ < 4; ++i_) {                                  \
                _Pragma("unroll")                                             \
                for (int j_ = 0; j_ < 4; ++j_)                                \
                    if (k0_ + i_ * 16 + j_ >= kl) wv_[4 * i_ + j_] = 0.0f;    \
            }                                                                 \
        }                                                                     \
        short8 wf0_, wf1_;                                                    \
        _Pragma("unroll")                                                     \
        for (int e_ = 0; e_ < 8; ++e_) {                                      \
            wf0_[e_] = (short)f2bf(wv_[e_]);                                  \
            wf1_[e_] = (short)f2bf(wv_[8 + e_]);                              \
        }                                                                     \
        const char* ab_ = lds + (BUF) * 16384 + lane * 16;                    \
        _Pragma("unroll")                                                     \
        for (int q_ = 0; q_ < 8; ++q_) {                                      \
            short8 a0_ = *(const short8*)(ab_ + q_ * 1024);                   \
            short8 a1_ = *(const short8*)(ab_ + 8192 + q_ * 1024);            \
            acc[q_] = __builtin_amdgcn_mfma_f32_16x16x32_bf16(                \
                wf0_, a0_, acc[q_], 0, 0, 0);                                 \
            acc[q_] = __builtin_amdgcn_mfma_f32_16x16x32_bf16(                \
                wf1_, a1_, acc[q_], 0, 0, 0);                                 \
        }                                                                     \
    }

    {
        int t = t0, buf = 0;
        STAGE_A(t, 0);
        ISSUE_W(t, wbA);
        while (true) {
            __syncthreads();
            bool pre = (t + 1 < t1);
            if (pre) { STAGE_A(t + 1, buf ^ 1); ISSUE_W(t + 1, wbB); }
            COMPUTE_L(t, buf, wbA);
            if (!pre) break;
            ++t; buf ^= 1;
            __syncthreads();
            pre = (t + 1 < t1);
            if (pre) { STAGE_A(t + 1, buf ^ 1); ISSUE_W(t + 1, wbA); }
            COMPUTE_L(t, buf, wbB);
            if (!pre) break;
            ++t; buf ^= 1;
        }
    }
#undef ISSUE_W
#undef STAGE_A
#undef COMPUTE_L

    // bf16 partial tile [128 rows][128 b] at this block's 32KB slot
    unsigned short* pc = partial + (size_t)blockIdx.x * 16384 +
                         (wid * 16 + kq * 4) * 128 + row;
#pragma unroll
    for (int q = 0; q < 8; ++q)
#pragma unroll
        for (int i = 0; i < 4; ++i)
            pc[(size_t)i * 128 + q * 16] = f2bf(acc[q][i]);
}

// reduce bf16 partial slots + bias + prelu -> bf16 fragment-order activations
__global__ void reduce01_k(const unsigned short* __restrict__ p,
                           const float* __restrict__ bias,
                           const float* __restrict__ alpha, unsigned short* __restrict__ h,
                           int M, int nseg, int excl, int CH) {
    int gid = blockIdx.x * 256 + threadIdx.x;   // (M/4)*128 threads
    int m0 = (gid >> 7) << 2;
    int b  = gid & 127;
    int tile_m = (M - 128 - (m0 & ~127)) >> 7;
    int basep = 0, cntm = 0;
    for (int tt = 0; tt <= tile_m; ++tt) {
        int nt = tile_nt(M, tt, nseg, excl);
        int cnt = (nt + CH - 1) / CH;
        if (tt == tile_m) cntm = cnt;
        else basep += cnt;
    }
    const unsigned short* ps = p + (size_t)basep * 16384 + (m0 & 127) * 128 + b;
    f32x4 v = {};
    for (int s = 0; s < cntm; ++s) {
        v[0] += bf2f(ps[0]);
        v[1] += bf2f(ps[128]);
        v[2] += bf2f(ps[256]);
        v[3] += bf2f(ps[384]);
        ps += 16384;
    }
    ushort4 st;
    float t;
    t = v[0] + bias[m0 + 0]; t = fmaxf(t, 0.f) + alpha[m0 + 0] * fminf(t, 0.f); st.x = f2bf(t);
    t = v[1] + bias[m0 + 1]; t = fmaxf(t, 0.f) + alpha[m0 + 1] * fminf(t, 0.f); st.y = f2bf(t);
    t = v[2] + bias[m0 + 2]; t = fmaxf(t, 0.f) + alpha[m0 + 2] * fminf(t, 0.f); st.z = f2bf(t);
    t = v[3] + bias[m0 + 3]; t = fmaxf(t, 0.f) + alpha[m0 + 3] * fminf(t, 0.f); st.w = f2bf(t);
    *(ushort4*)&h[fidx(m0, b)] = st;
}

// reduce bf16 partial slots + bias + sigmoid + unfold scatter -> out[b][site]
__global__ void reduce2_k(const unsigned short* __restrict__ p,
                          const float* __restrict__ b2,
                          float* __restrict__ out, int CH) {
    int gid = blockIdx.x * 256 + threadIdx.x;   // NN*BB threads, n-major
    int n = gid >> 7;
    int b = gid & 127;
    int tile_m = (NN - 128 - (n & ~127)) >> 7;
    int basep = 0, cntm = 0;
    for (int tt = 0; tt <= tile_m; ++tt) {
        int nt = tile_nt(NN, tt, 2, 0);
        int cnt = (nt + CH - 1) / CH;
        if (tt == tile_m) cntm = cnt;
        else basep += cnt;
    }
    const unsigned short* ps = p + (size_t)basep * 16384 + (n & 127) * 128 + b;
    float v = 0.0f;
    for (int s = 0; s < cntm; ++s) { v += bf2f(*ps); ps += 16384; }
    v += b2[n];
    float sg = 1.0f / (1.0f + __expf(-v));
    if (n == 0) sg = 0.5f;
    out[(size_t)b * NN + perm_site(n)] = sg;
}

// ---------------- host ----------------
static inline void h_klims(int r, int& S, int& E) {
    if (r == 0) { S = 0; E = 1; return; }
    int j = (31 - __builtin_clz((unsigned)r)) >> 1;
    int g = r >> (2 * j);
    S = g << (2 * j);
    E = (g + 1) << (2 * j);
}

static inline int grid_for(int M, int nseg, int excl, int CH) {
    int nb = 0;
    for (int tile = 0; tile < M / 128; ++tile) {
        int r_top = (M - 1 - tile * 128) & (NN - 1);
        int S, E;
        h_klims(r_top, S, E);
        int kmax = excl ? S : E;
        int nt = nseg * ((kmax + 63) >> 6);
        nb += (nt + CH - 1) / CH;
    }
    return nb;
}

// smallest CH with grid <= cap AND partial buffer fits -> largest grid <= cap
static inline int pick_ch(int M, int nseg, int excl, int cap, size_t ws_avail,
                          int* g_out) {
    for (int ch = 2; ch <= 4096; ++ch) {
        int g = grid_for(M, nseg, excl, ch);
        if (g <= cap && (size_t)g * 32768 <= ws_avail) {
            *g_out = g;
            return ch;
        }
    }
    *g_out = grid_for(M, nseg, excl, 4096);
    return 4096;
}

extern "C" void kernel_launch(void* const* d_in, const int* in_sizes, int n_in,
                              void* d_out, int out_size, void* d_ws, size_t ws_size,
                              hipStream_t stream) {
    const float* x  = (const float*)d_in[0];
    const float* W0 = (const float*)d_in[1];
    const float* b0 = (const float*)d_in[2];
    const float* a1 = (const float*)d_in[3];
    const float* W1 = (const float*)d_in[4];
    const float* b1 = (const float*)d_in[5];
    const float* a2 = (const float*)d_in[6];
    const float* W2 = (const float*)d_in[7];
    const float* b2 = (const float*)d_in[8];

    char* ws = (char*)d_ws;
    unsigned short* xf = (unsigned short*)ws;                 // 1 MB
    unsigned short* h0 = (unsigned short*)(ws + (1 << 20));   // 2 MB
    unsigned short* h1 = (unsigned short*)(ws + (3 << 20));   // 2 MB
    unsigned short* pp = (unsigned short*)(ws + (5 << 20));   // bf16 partials (32KB/slot)

    size_t avail = ws_size > (5u << 20) ? ws_size - (5u << 20) : 0;
    int g0, g1, g2;
    int CH0 = pick_ch(2 * NN, 1, 1, 512, avail, &g0);
    int CH1 = pick_ch(2 * NN, 2, 0, 512, avail, &g1);
    int CH2 = pick_ch(NN, 2, 0, 512, avail, &g2);

    fold_k<<<2048, 256, 0, stream>>>(x, xf);

    made_gemm21<true><<<g0, 512, 0, stream>>>(xf, W0, pp, 2 * NN, NN, 1, CH0);
    reduce01_k<<<1024, 256, 0, stream>>>(pp, b0, a1, h0, 2 * NN, 1, 1, CH0);

    made_gemm21<false><<<g1, 512, 0, stream>>>(h0, W1, pp, 2 * NN, 2 * NN, 2, CH1);
    reduce01_k<<<1024, 256, 0, stream>>>(pp, b1, a2, h1, 2 * NN, 2, 0, CH1);

    made_gemm21<false><<<g2, 512, 0, stream>>>(h1, W2, pp, NN, 2 * NN, 2, CH2);
    reduce2_k<<<2048, 256, 0, stream>>>(pp, b2, (float*)d_out, CH2);
}

// Round 22
// 138.248 us; speedup vs baseline: 1.1383x; 1.1121x over previous
//
#include <hip/hip_runtime.h>
#include <hip/hip_bf16.h>
#include <cstddef>
#include <cstdint>

#define NN 4096
#define BB 128

using short8 = __attribute__((ext_vector_type(8))) short;
using f32x4  = __attribute__((ext_vector_type(4))) float;

__device__ __forceinline__ void klims(int r, int& S, int& E) {
    if (r == 0) { S = 0; E = 1; return; }
    int j = (31 - __clz(r)) >> 1;
    int g = r >> (2 * j);
    S = g << (2 * j);
    E = (g + 1) << (2 * j);
}

__device__ __forceinline__ int perm_site(int n) {
    if (n == 0) return 0;
    int j = (31 - __clz(n)) >> 1;
    int g = n >> (2 * j);
    int o = n - (g << (2 * j));
    int side = 1 << j;
    int rr = o >> j, cc = o & (side - 1);
    int i = 5 - j;
    int s = 1 << i, p = 1 << (i + 1);
    int r, c;
    if (g == 1)      { r = s + rr * p; c = s + cc * p; }
    else if (g == 2) { r = s + rr * p; c = cc * p;     }
    else             { r = rr * p;     c = s + cc * p; }
    return r * 64 + c;
}

__device__ __forceinline__ int inv_site(int s) {
    if (s == 0) return 0;
    int r = s >> 6, c = s & 63;
    int ir = r ? __builtin_ctz(r) : 6;
    int ic = c ? __builtin_ctz(c) : 6;
    int i = ir < ic ? ir : ic;
    int j = 5 - i;
    int rb = (r >> i) & 1, cb = (c >> i) & 1;
    int g = rb ? (cb ? 1 : 2) : 3;
    return (g << (2 * j)) + ((r >> (i + 1)) << j) + (c >> (i + 1));
}

__device__ __forceinline__ size_t fidx(int k, int b) {
    return (size_t)(((k >> 5) * 8 + (b >> 4)) * 512 + ((k >> 2) & 3) * 128 +
                    (b & 15) * 8 + ((k >> 4) & 1) * 4 + (k & 3));
}

__device__ __forceinline__ unsigned short f2bf(float f) {
    __hip_bfloat16 h = __float2bfloat16(f);
    return __builtin_bit_cast(unsigned short, h);
}

__device__ __forceinline__ float bf2f(unsigned short u) {
    unsigned v = (unsigned)u << 16;
    return __builtin_bit_cast(float, v);
}

__device__ __forceinline__ void gload_lds16(const void* g, void* l) {
    __builtin_amdgcn_global_load_lds(
        (const __attribute__((address_space(1))) unsigned int*)g,
        (__attribute__((address_space(3))) unsigned int*)l, 16, 0, 0);
}

__device__ __forceinline__ int tile_nt(int M, int tile, int nseg, int excl) {
    int r_top = (M - 1 - tile * 128) & (NN - 1);
    int S, E;
    klims(r_top, S, E);
    int kmax = excl ? S : E;
    return nseg * ((kmax + 63) >> 6);
}

// fold: xf_frag[n][b] = x[b][site(n)] as bf16, coalesced reads over x
__global__ void fold_k(const float* __restrict__ x, unsigned short* __restrict__ xf) {
    int gid = blockIdx.x * 256 + threadIdx.x;  // b*4096 + s
    int b = gid >> 12, s = gid & 4095;
    float v = x[gid];
    int n = inv_site(s);
    xf[fidx(n, b)] = f2bf(v);
}

// Masked GEMM (champion body): flattened queue, A LDS-staged dbuf,
// W 2-deep reg prefetch, bf16 partials. CH tuned per layer so grid <= 512
// (one dispatch round: no tail, full utilization).
template <bool EXCL>
__global__ __launch_bounds__(512, 2) void made_gemm19(
        const unsigned short* __restrict__ A, const float* __restrict__ W,
        unsigned short* __restrict__ partial, int M, int Ktot, int nseg, int CH) {
    __shared__ __align__(16) char lds[32768];   // 2 x 16KB A k-step buffers

    int b = (int)blockIdx.x, tile = 0, base = 0, nt = 0;
    for (;;) {
        nt = tile_nt(M, tile, nseg, EXCL ? 1 : 0);
        int cnt = (nt + CH - 1) / CH;
        if (b < base + cnt) break;
        base += cnt;
        ++tile;
    }
    const int nkt = nt / nseg;
    const int t0 = (b - base) * CH;
    const int t1 = (t0 + CH < nt) ? t0 + CH : nt;

    const int tid  = threadIdx.x;
    const int wid  = tid >> 6;
    const int lane = tid & 63;
    const int r0   = M - 128 - tile * 128;
    const int rw0  = r0 + wid * 16;
    const int rch  = rw0 & (NN - 1);
    const int row  = lane & 15;
    const int kq   = lane >> 4;

    int S, E;
    klims(rch + row, S, E);
    const int kl = EXCL ? S : E;
    klims(rch, S, E);
    const int wkmin = EXCL ? S : E;

    f32x4 acc[8] = {};
    const float* wrow = W + (size_t)(rw0 + row) * Ktot + kq * 4;
    const char* Ab = (const char*)A;

    float4 wbA[4], wbB[4];

#define ISSUE_W(T, WB)                                                        \
    {                                                                         \
        int sg_ = (nseg == 2 && (T) >= nkt) ? 1 : 0;                          \
        const float* wp_ = wrow + sg_ * NN + (((T) - sg_ * nkt) << 6);        \
        WB[0] = *(const float4*)(wp_);                                        \
        WB[1] = *(const float4*)(wp_ + 16);                                   \
        WB[2] = *(const float4*)(wp_ + 32);                                   \
        WB[3] = *(const float4*)(wp_ + 48);                                   \
    }

#define STAGE_A(T, BUF)                                                       \
    {                                                                         \
        int sg_ = (nseg == 2 && (T) >= nkt) ? 1 : 0;                          \
        int kb_ = ((T) - sg_ * nkt) << 6;                                     \
        const char* src_ = Ab + (size_t)(sg_ * NN + kb_) * 256 +              \
                           wid * 2048 + lane * 16;                            \
        char* dst_ = lds + (BUF) * 16384 + wid * 2048;                        \
        gload_lds16(src_, dst_);                                              \
        gload_lds16(src_ + 1024, dst_ + 1024);                                \
    }

#define COMPUTE_L(T, BUF, WB)                                                 \
    {                                                                         \
        int kb_ = (((T) >= nkt && nseg == 2) ? (T) - nkt : (T)) << 6;         \
        float wv_[16];                                                        \
        _Pragma("unroll")                                                     \
        for (int i_ = 0; i_ < 4; ++i_) {                                      \
            wv_[4 * i_ + 0] = WB[i_].x;                                       \
            wv_[4 * i_ + 1] = WB[i_].y;                                       \
            wv_[4 * i_ + 2] = WB[i_].z;                                       \
            wv_[4 * i_ + 3] = WB[i_].w;                                       \
        }                                                                     \
        if (kb_ + 64 > wkmin) {                                               \
            int k0_ = kb_ + kq * 4;                                           \
            _Pragma("unroll")                                                 \
            for (int i_ = 0; i_ < 4; ++i_) {                                  \
                _Pragma("unroll")                                             \
                for (int j_ = 0; j_ < 4; ++j_)                                \
                    if (k0_ + i_ * 16 + j_ >= kl) wv_[4 * i_ + j_] = 0.0f;    \
            }                                                                 \
        }                                                                     \
        short8 wf0_, wf1_;                                                    \
        _Pragma("unroll")                                                     \
        for (int e_ = 0; e_ < 8; ++e_) {                                      \
            wf0_[e_] = (short)f2bf(wv_[e_]);                                  \
            wf1_[e_] = (short)f2bf(wv_[8 + e_]);                              \
        }                                                                     \
        const char* ab_ = lds + (BUF) * 16384 + lane * 16;                    \
        _Pragma("unroll")                                                     \
        for (int q_ = 0; q_ < 8; ++q_) {                                      \
            short8 a0_ = *(const short8*)(ab_ + q_ * 1024);                   \
            short8 a1_ = *(const short8*)(ab_ + 8192 + q_ * 1024);            \
            acc[q_] = __builtin_amdgcn_mfma_f32_16x16x32_bf16(                \
                wf0_, a0_, acc[q_], 0, 0, 0);                                 \
            acc[q_] = __builtin_amdgcn_mfma_f32_16x16x32_bf16(                \
                wf1_, a1_, acc[q_], 0, 0, 0);                                 \
        }                                                                     \
    }

    {
        int t = t0, buf = 0;
        STAGE_A(t, 0);
        ISSUE_W(t, wbA);
        while (true) {
            __syncthreads();
            bool pre = (t + 1 < t1);
            if (pre) { STAGE_A(t + 1, buf ^ 1); ISSUE_W(t + 1, wbB); }
            COMPUTE_L(t, buf, wbA);
            if (!pre) break;
            ++t; buf ^= 1;
            __syncthreads();
            pre = (t + 1 < t1);
            if (pre) { STAGE_A(t + 1, buf ^ 1); ISSUE_W(t + 1, wbA); }
            COMPUTE_L(t, buf, wbB);
            if (!pre) break;
            ++t; buf ^= 1;
        }
    }
#undef ISSUE_W
#undef STAGE_A
#undef COMPUTE_L

    // bf16 partial tile [128 rows][128 b] at this block's 32KB slot
    unsigned short* pc = partial + (size_t)blockIdx.x * 16384 +
                         (wid * 16 + kq * 4) * 128 + row;
#pragma unroll
    for (int q = 0; q < 8; ++q)
#pragma unroll
        for (int i = 0; i < 4; ++i)
            pc[(size_t)i * 128 + q * 16] = f2bf(acc[q][i]);
}

// reduce bf16 partial slots + bias + prelu -> bf16 fragment-order activations
__global__ void reduce01_k(const unsigned short* __restrict__ p,
                           const float* __restrict__ bias,
                           const float* __restrict__ alpha, unsigned short* __restrict__ h,
                           int M, int nseg, int excl, int CH) {
    int gid = blockIdx.x * 256 + threadIdx.x;   // (M/4)*128 threads
    int m0 = (gid >> 7) << 2;
    int b  = gid & 127;
    int tile_m = (M - 128 - (m0 & ~127)) >> 7;
    int basep = 0, cntm = 0;
    for (int tt = 0; tt <= tile_m; ++tt) {
        int nt = tile_nt(M, tt, nseg, excl);
        int cnt = (nt + CH - 1) / CH;
        if (tt == tile_m) cntm = cnt;
        else basep += cnt;
    }
    const unsigned short* ps = p + (size_t)basep * 16384 + (m0 & 127) * 128 + b;
    f32x4 v = {};
    for (int s = 0; s < cntm; ++s) {
        v[0] += bf2f(ps[0]);
        v[1] += bf2f(ps[128]);
        v[2] += bf2f(ps[256]);
        v[3] += bf2f(ps[384]);
        ps += 16384;
    }
    ushort4 st;
    float t;
    t = v[0] + bias[m0 + 0]; t = fmaxf(t, 0.f) + alpha[m0 + 0] * fminf(t, 0.f); st.x = f2bf(t);
    t = v[1] + bias[m0 + 1]; t = fmaxf(t, 0.f) + alpha[m0 + 1] * fminf(t, 0.f); st.y = f2bf(t);
    t = v[2] + bias[m0 + 2]; t = fmaxf(t, 0.f) + alpha[m0 + 2] * fminf(t, 0.f); st.z = f2bf(t);
    t = v[3] + bias[m0 + 3]; t = fmaxf(t, 0.f) + alpha[m0 + 3] * fminf(t, 0.f); st.w = f2bf(t);
    *(ushort4*)&h[fidx(m0, b)] = st;
}

// reduce bf16 partial slots + bias + sigmoid + unfold scatter -> out[b][site]
__global__ void reduce2_k(const unsigned short* __restrict__ p,
                          const float* __restrict__ b2,
                          float* __restrict__ out, int CH) {
    int gid = blockIdx.x * 256 + threadIdx.x;   // NN*BB threads, n-major
    int n = gid >> 7;
    int b = gid & 127;
    int tile_m = (NN - 128 - (n & ~127)) >> 7;
    int basep = 0, cntm = 0;
    for (int tt = 0; tt <= tile_m; ++tt) {
        int nt = tile_nt(NN, tt, 2, 0);
        int cnt = (nt + CH - 1) / CH;
        if (tt == tile_m) cntm = cnt;
        else basep += cnt;
    }
    const unsigned short* ps = p + (size_t)basep * 16384 + (n & 127) * 128 + b;
    float v = 0.0f;
    for (int s = 0; s < cntm; ++s) { v += bf2f(*ps); ps += 16384; }
    v += b2[n];
    float sg = 1.0f / (1.0f + __expf(-v));
    if (n == 0) sg = 0.5f;
    out[(size_t)b * NN + perm_site(n)] = sg;
}

// ---------------- host ----------------
static inline void h_klims(int r, int& S, int& E) {
    if (r == 0) { S = 0; E = 1; return; }
    int j = (31 - __builtin_clz((unsigned)r)) >> 1;
    int g = r >> (2 * j);
    S = g << (2 * j);
    E = (g + 1) << (2 * j);
}

static inline int grid_for(int M, int nseg, int excl, int CH) {
    int nb = 0;
    for (int tile = 0; tile < M / 128; ++tile) {
        int r_top = (M - 1 - tile * 128) & (NN - 1);
        int S, E;
        h_klims(r_top, S, E);
        int kmax = excl ? S : E;
        int nt = nseg * ((kmax + 63) >> 6);
        nb += (nt + CH - 1) / CH;
    }
    return nb;
}

// smallest CH with grid <= cap AND partial buffer fits -> largest grid <= cap
static inline int pick_ch(int M, int nseg, int excl, int cap, size_t ws_avail,
                          int* g_out) {
    for (int ch = 2; ch <= 4096; ++ch) {
        int g = grid_for(M, nseg, excl, ch);
        if (g <= cap && (size_t)g * 32768 <= ws_avail) {
            *g_out = g;
            return ch;
        }
    }
    *g_out = grid_for(M, nseg, excl, 4096);
    return 4096;
}

extern "C" void kernel_launch(void* const* d_in, const int* in_sizes, int n_in,
                              void* d_out, int out_size, void* d_ws, size_t ws_size,
                              hipStream_t stream) {
    const float* x  = (const float*)d_in[0];
    const float* W0 = (const float*)d_in[1];
    const float* b0 = (const float*)d_in[2];
    const float* a1 = (const float*)d_in[3];
    const float* W1 = (const float*)d_in[4];
    const float* b1 = (const float*)d_in[5];
    const float* a2 = (const float*)d_in[6];
    const float* W2 = (const float*)d_in[7];
    const float* b2 = (const float*)d_in[8];

    char* ws = (char*)d_ws;
    unsigned short* xf = (unsigned short*)ws;                 // 1 MB
    unsigned short* h0 = (unsigned short*)(ws + (1 << 20));   // 2 MB
    unsigned short* h1 = (unsigned short*)(ws + (3 << 20));   // 2 MB
    unsigned short* pp = (unsigned short*)(ws + (5 << 20));   // bf16 partials (32KB/slot)

    size_t avail = ws_size > (5u << 20) ? ws_size - (5u << 20) : 0;
    int g0, g1, g2;
    int CH0 = pick_ch(2 * NN, 1, 1, 512, avail, &g0);
    int CH1 = pick_ch(2 * NN, 2, 0, 512, avail, &g1);
    int CH2 = pick_ch(NN, 2, 0, 512, avail, &g2);

    fold_k<<<2048, 256, 0, stream>>>(x, xf);

    made_gemm19<true><<<g0, 512, 0, stream>>>(xf, W0, pp, 2 * NN, NN, 1, CH0);
    reduce01_k<<<1024, 256, 0, stream>>>(pp, b0, a1, h0, 2 * NN, 1, 1, CH0);

    made_gemm19<false><<<g1, 512, 0, stream>>>(h0, W1, pp, 2 * NN, 2 * NN, 2, CH1);
    reduce01_k<<<1024, 256, 0, stream>>>(pp, b1, a2, h1, 2 * NN, 2, 0, CH1);

    made_gemm19<false><<<g2, 512, 0, stream>>>(h1, W2, pp, NN, 2 * NN, 2, CH2);
    reduce2_k<<<2048, 256, 0, stream>>>(pp, b2, (float*)d_out, CH2);
}